// Round 7
// baseline (342.159 us; speedup 1.0000x reference)
//
#include <hip/hip_runtime.h>
#include <hip/hip_bf16.h>

// ComplexAttention: B=2, L=2048, D=1024, H=16, HD=64, SCALE=0.125
// Pipeline: pack(x,w) -> bf16 GEMM (QKV: 256x192, 32x32x16 MFMA, pipelined phases,
//           2-ahead post-barrier staging) -> flash attn (8-wave paired q-tiles)
//           -> bf16 GEMM (out: 128x256 pipelined, 1-round grid).
// All LDS tiles staged via global_load_lds(16B) with XOR-16B-chunk swizzle
// (chunk' = chunk ^ (row&7)) folded into the GLOBAL address so LDS stays
// contiguous (wave-uniform base + lane*16 contract) yet frag reads are ~conflict-free.
// RACE DISCIPLINE (r5 lesson): DMA into a double-buffer slot is issued ONLY after the
// barrier that retires it — never pre-barrier (lagging waves may still read it).

using f32x4  = __attribute__((ext_vector_type(4))) float;
using f32x16 = __attribute__((ext_vector_type(16))) float;  // 32x32 MFMA C/D
using short8 = __attribute__((ext_vector_type(8))) short;   // 8 bf16 = 4 VGPRs (MFMA A/B frag)
using bf16_t = __hip_bfloat16;

#define AS1 __attribute__((address_space(1)))
#define AS3 __attribute__((address_space(3)))

__device__ __forceinline__ void gload_lds16(const bf16_t* g, bf16_t* l) {
  __builtin_amdgcn_global_load_lds((const AS1 unsigned int*)g, (AS3 unsigned int*)l, 16, 0, 0);
}

__device__ __forceinline__ unsigned short bfbits(float f) {
  union { bf16_t h; unsigned short u; } c; c.h = __float2bfloat16(f); return c.u;
}

// ---------------------------------------------------------------- pack kernels
__global__ void pack_x_k(const float* __restrict__ xr, const float* __restrict__ xi,
                         bf16_t* __restrict__ out) {
  const int total4 = 4096 * 2048 / 4;
  for (int idx = blockIdx.x * blockDim.x + threadIdx.x; idx < total4;
       idx += gridDim.x * blockDim.x) {
    int m = idx >> 9, k = (idx & 511) * 4;
    const float* src = (k < 1024) ? (xr + (size_t)m * 1024 + k)
                                  : (xi + (size_t)m * 1024 + (k - 1024));
    float4 v = *(const float4*)src;
    unsigned int lo = (unsigned)bfbits(v.x) | ((unsigned)bfbits(v.y) << 16);
    unsigned int hi = (unsigned)bfbits(v.z) | ((unsigned)bfbits(v.w) << 16);
    *(uint2*)(out + (size_t)idx * 4) = make_uint2(lo, hi);
  }
}

__global__ void pack_wqkv_k(const float* __restrict__ wqr, const float* __restrict__ wqi,
                            const float* __restrict__ wkr, const float* __restrict__ wki,
                            const float* __restrict__ wvr, const float* __restrict__ wvi,
                            bf16_t* __restrict__ out) {
  const int total4 = 6144 * 2048 / 4;
  for (int idx = blockIdx.x * blockDim.x + threadIdx.x; idx < total4;
       idx += gridDim.x * blockDim.x) {
    int row = idx >> 9, k = (idx & 511) * 4;
    int sec = row >> 10, r1 = row & 1023;
    bool lowk = (k < 1024);
    int kk = lowk ? k : (k - 1024);
    const float* base = wqr; float sg = 1.f;
    switch (sec) {
      case 0: base = lowk ? wqr : wqi; sg = lowk ? 1.f : -1.f; break;
      case 1: base = lowk ? wqi : wqr; break;
      case 2: base = lowk ? wkr : wki; sg = lowk ? 1.f : -1.f; break;
      case 3: base = lowk ? wki : wkr; break;
      case 4: base = lowk ? wvr : wvi; sg = lowk ? 1.f : -1.f; break;
      case 5: base = lowk ? wvi : wvr; break;
    }
    float4 v = *(const float4*)(base + (size_t)r1 * 1024 + kk);
    unsigned int lo = (unsigned)bfbits(v.x * sg) | ((unsigned)bfbits(v.y * sg) << 16);
    unsigned int hi = (unsigned)bfbits(v.z * sg) | ((unsigned)bfbits(v.w * sg) << 16);
    *(uint2*)(out + (size_t)idx * 4) = make_uint2(lo, hi);
  }
}

__global__ void pack_wo_k(const float* __restrict__ wor, const float* __restrict__ woi,
                          bf16_t* __restrict__ out) {
  const int total4 = 2048 * 2048 / 4;
  for (int idx = blockIdx.x * blockDim.x + threadIdx.x; idx < total4;
       idx += gridDim.x * blockDim.x) {
    int row = idx >> 9, k = (idx & 511) * 4;
    int sec = row >> 10, r1 = row & 1023;
    bool lowk = (k < 1024);
    int kk = lowk ? k : (k - 1024);
    const float* base; float sg = 1.f;
    if (sec == 0) { base = lowk ? wor : woi; sg = lowk ? 1.f : -1.f; }
    else          { base = lowk ? woi : wor; }
    float4 v = *(const float4*)(base + (size_t)r1 * 1024 + kk);
    unsigned int lo = (unsigned)bfbits(v.x * sg) | ((unsigned)bfbits(v.y * sg) << 16);
    unsigned int hi = (unsigned)bfbits(v.z * sg) | ((unsigned)bfbits(v.w * sg) << 16);
    *(uint2*)(out + (size_t)idx * 4) = make_uint2(lo, hi);
  }
}

// ---------------------------------------------------------------- QKV GEMM: 256x192, 32x32x16
// C[m,n] = sum_k A[m,k]*W[n,k]; A: 4096x2048, W: 6144x2048. Grid (16,32) = 512 blocks =
// 2 rounds. 8 waves as 4M x 2N: per-wave 64x96 = 2x3 C-tiles of 32x32 (acc 6 x f32x16 =
// 96 VGPR). BK=64 = 4 k-steps of 16. Frag layout (32x32x16): A/B row|col = lane&31,
// k = (lane>>5)*8 + j; C/D col = lane&31, row = (r&3) + 8*(r>>2) + 4*(lane>>5).
// LDS row = 64 elem = 8 chunks; frag read chunk = (2*ks + (lane>>5)) ^ (row&7) — 64 lanes
// hit 64 distinct chunks, bank-balanced. 5 reads + 6 MFMA per phase (balanced pipes).
// Pipelined skeleton (reads one phase ahead of their MFMA):
//   ph0: read Y(ks1)     | MFMA X(ks0)
//   ph1: read X(ks2)     | MFMA Y(ks1)
//   ph2: read Y(ks3)     | MFMA X(ks2)
//   boundary: vmcnt(0) + s_barrier  (drains exactly tile t+1's 9 loads, issued ph3 of
//                                    t-1, ~4 phases earlier -> latency covered)
//   ph3: read X(ks0) of t+1 from q | stage ALL of t+2 -> p (post-barrier: p dead) | MFMA Y(ks3)
// cols 0..4095 -> qk (Qr|Qi|Kr|Ki, Q pre-scaled); 4096..6143 -> V transposed.
__global__ __launch_bounds__(512, 2) void gemm_qkv_k(const bf16_t* __restrict__ A,
                                                     const bf16_t* __restrict__ W,
                                                     bf16_t* __restrict__ qk,
                                                     bf16_t* __restrict__ vt) {
  __shared__ __align__(16) bf16_t sA[2][256 * 64];  // 64 KB
  __shared__ __align__(16) bf16_t sB[2][192 * 64];  // 48 KB
  const int tid = threadIdx.x, lane = tid & 63, w = tid >> 6;
  const int wm = w >> 1, wn = w & 1;                // 4M x 2N
  const int l31 = lane & 31, h5 = lane >> 5;
  const int swz = l31 & 7;                          // row&7 for frag reads
  const int m0 = blockIdx.x * 256, n0 = blockIdx.y * 192;
  const int NT = 32;

  const int l3 = lane >> 3;
  const int gcol = (((lane & 7) ^ l3) * 8);

  f32x16 acc[2][3] = {};

  auto stageA = [&](int buf, int half, int k0) {   // one 128-row half, 2 instr/wave
#pragma unroll
    for (int i = 0; i < 2; ++i)
      gload_lds16(A + (size_t)(m0 + half * 128 + w * 16 + i * 8 + l3) * 2048 + k0 + gcol,
                  &sA[buf][(size_t)(half * 128 + w * 16 + i * 8) * 64] + lane * 8);
  };
  auto stageB = [&](int buf, int c, int k0) {      // 64-row chunk c, 1 instr/wave
    gload_lds16(W + (size_t)(n0 + c * 64 + w * 8 + l3) * 2048 + k0 + gcol,
                &sB[buf][(size_t)(c * 64 + w * 8) * 64] + lane * 8);
  };
  // 32x32 frag reads: row = base + l31 (base mult of 32 -> row&7 = l31&7)
  auto rdA = [&](const bf16_t* sAx, int mt, int ks) -> short8 {
    return *(const short8*)(sAx + (wm * 64 + mt * 32 + l31) * 64 +
                            (((ks * 2 + h5) ^ swz) * 8));
  };
  auto rdB = [&](const bf16_t* sBx, int nt, int ks) -> short8 {
    return *(const short8*)(sBx + (wn * 96 + nt * 32 + l31) * 64 +
                            (((ks * 2 + h5) ^ swz) * 8));
  };

  // prologue: stage tiles 0 and 1 fully; drain tile 0 (leave tile 1's 7 in flight).
  stageA(0, 0, 0); stageA(0, 1, 0);
  stageB(0, 0, 0); stageB(0, 1, 0); stageB(0, 2, 0);
  stageA(1, 0, 64); stageA(1, 1, 64);
  stageB(1, 0, 64); stageB(1, 1, 64); stageB(1, 2, 64);
  asm volatile("s_waitcnt vmcnt(7)" ::: "memory");
  __builtin_amdgcn_s_barrier();

  short8 AX[2], BX[3], AY[2], BY[3];
#pragma unroll
  for (int i = 0; i < 2; ++i) AX[i] = rdA(sA[0], i, 0);
#pragma unroll
  for (int j = 0; j < 3; ++j) BX[j] = rdB(sB[0], j, 0);

  for (int t = 0; t < NT; ++t) {
    const int p = t & 1, q = p ^ 1;
    const bf16_t* sAp = sA[p];
    const bf16_t* sBp = sB[p];
    const bf16_t* sAq = sA[q];
    const bf16_t* sBq = sB[q];
    const bool stg = (t + 1 < NT);
    const bool stg2 = (t + 2 < NT);

    // ---- ph0: read Y(ks1); MFMA X(ks0)
#pragma unroll
    for (int i = 0; i < 2; ++i) AY[i] = rdA(sAp, i, 1);
#pragma unroll
    for (int j = 0; j < 3; ++j) BY[j] = rdB(sBp, j, 1);
    __builtin_amdgcn_s_setprio(1);
#pragma unroll
    for (int i = 0; i < 2; ++i)
#pragma unroll
      for (int j = 0; j < 3; ++j)
        acc[i][j] = __builtin_amdgcn_mfma_f32_32x32x16_bf16(AX[i], BX[j], acc[i][j], 0, 0, 0);
    __builtin_amdgcn_s_setprio(0);

    // ---- ph1: read X(ks2); MFMA Y(ks1)
#pragma unroll
    for (int i = 0; i < 2; ++i) AX[i] = rdA(sAp, i, 2);
#pragma unroll
    for (int j = 0; j < 3; ++j) BX[j] = rdB(sBp, j, 2);
    __builtin_amdgcn_s_setprio(1);
#pragma unroll
    for (int i = 0; i < 2; ++i)
#pragma unroll
      for (int j = 0; j < 3; ++j)
        acc[i][j] = __builtin_amdgcn_mfma_f32_32x32x16_bf16(AY[i], BY[j], acc[i][j], 0, 0, 0);
    __builtin_amdgcn_s_setprio(0);

    // ---- ph2: read Y(ks3); MFMA X(ks2)
#pragma unroll
    for (int i = 0; i < 2; ++i) AY[i] = rdA(sAp, i, 3);
#pragma unroll
    for (int j = 0; j < 3; ++j) BY[j] = rdB(sBp, j, 3);
    __builtin_amdgcn_s_setprio(1);
#pragma unroll
    for (int i = 0; i < 2; ++i)
#pragma unroll
      for (int j = 0; j < 3; ++j)
        acc[i][j] = __builtin_amdgcn_mfma_f32_32x32x16_bf16(AX[i], BX[j], acc[i][j], 0, 0, 0);
    __builtin_amdgcn_s_setprio(0);

    // ---- tile boundary: exact drain of tile t+1's staging (issued ph3 of t-1)
    asm volatile("s_waitcnt vmcnt(0)" ::: "memory");
    __builtin_amdgcn_s_barrier();

    // ---- ph3: read X(ks0) of t+1 from q; stage ALL of tile t+2 -> p; MFMA Y(ks3)
    if (stg) {
#pragma unroll
      for (int i = 0; i < 2; ++i) AX[i] = rdA(sAq, i, 0);
#pragma unroll
      for (int j = 0; j < 3; ++j) BX[j] = rdB(sBq, j, 0);
    }
    if (stg2) {
      stageA(p, 0, (t + 2) * 64); stageA(p, 1, (t + 2) * 64);
      stageB(p, 0, (t + 2) * 64); stageB(p, 1, (t + 2) * 64); stageB(p, 2, (t + 2) * 64);
    }
    __builtin_amdgcn_s_setprio(1);
#pragma unroll
    for (int i = 0; i < 2; ++i)
#pragma unroll
      for (int j = 0; j < 3; ++j)
        acc[i][j] = __builtin_amdgcn_mfma_f32_32x32x16_bf16(AY[i], BY[j], acc[i][j], 0, 0, 0);
    __builtin_amdgcn_s_setprio(0);
  }

  // epilogue: C/D row = (r&3) + 8*(r>>2) + 4*h5, col = l31. Reg-quad rq spans 4
  // consecutive rows (rowb+0..3) at fixed col -> same store patterns as before.
#pragma unroll
  for (int mt = 0; mt < 2; ++mt) {
#pragma unroll
    for (int nt = 0; nt < 3; ++nt) {
      const int col = n0 + wn * 96 + nt * 32 + l31;     // uniform <4096 check per nt
#pragma unroll
      for (int rq = 0; rq < 4; ++rq) {
        const int rowb = m0 + wm * 64 + mt * 32 + rq * 8 + h5 * 4;
        if (col < 4096) {
          const float sc = (col < 2048) ? 0.125f : 1.f;  // pre-scale Q by SCALE
#pragma unroll
          for (int s = 0; s < 4; ++s)
            qk[(size_t)(rowb + s) * 4096 + col] = __float2bfloat16(acc[mt][nt][rq * 4 + s] * sc);
        } else {
          const int vcol = col - 4096;
          const int ri = vcol >> 10, dfeat = vcol & 1023;
          const int b = rowb >> 11, seq = rowb & 2047;
          const size_t vrow = (size_t)(b * 2048 + (dfeat >> 6) * 128 + ri * 64 + (dfeat & 63));
          unsigned int lo = (unsigned)bfbits(acc[mt][nt][rq * 4 + 0]) |
                            ((unsigned)bfbits(acc[mt][nt][rq * 4 + 1]) << 16);
          unsigned int hi = (unsigned)bfbits(acc[mt][nt][rq * 4 + 2]) |
                            ((unsigned)bfbits(acc[mt][nt][rq * 4 + 3]) << 16);
          *(uint2*)(vt + vrow * 2048 + seq) = make_uint2(lo, hi);
        }
      }
    }
  }
}

// ---------------------------------------------------------------- Output GEMM: 128x256, pipelined
// C = Acat(4096x2048) x Wo(2048x2048)^T, fp32 out + bias. Grid (32,8) = 256 blocks =
// exactly 1 round. 8 waves (2M x 4N), per-wave 64x64 = acc[4][4]. All tile-(t+2)
// staging at ph3 post-barrier; boundary vmcnt(0) drains exactly tile t+1's 6 loads.
// LDS 96 KiB (sA 2x16K + sB 2x32K), 1 block/CU.
__global__ __launch_bounds__(512, 2) void gemm_out_k(const bf16_t* __restrict__ A,
                                                     const bf16_t* __restrict__ W,
                                                     const float* __restrict__ bor,
                                                     const float* __restrict__ boi,
                                                     float* __restrict__ out) {
  __shared__ __align__(16) bf16_t sA[2][128 * 64];  // 32 KB
  __shared__ __align__(16) bf16_t sB[2][256 * 64];  // 64 KB
  const int tid = threadIdx.x, lane = tid & 63, w = tid >> 6;
  const int wm = w >> 2, wn = w & 3;
  const int quad = lane >> 4, m16 = lane & 15;
  const int swz7 = m16 & 7;
  const int m0 = blockIdx.x * 128, n0 = blockIdx.y * 256;
  const int NT = 32;

  const int l3 = lane >> 3;
  const int gcol = (((lane & 7) ^ l3) * 8);

  f32x4 acc[4][4] = {};

  auto stageA = [&](int buf, int k0) {             // 128 rows, 2 instr/wave
#pragma unroll
    for (int i = 0; i < 2; ++i)
      gload_lds16(A + (size_t)(m0 + w * 16 + i * 8 + l3) * 2048 + k0 + gcol,
                  &sA[buf][(size_t)(w * 16 + i * 8) * 64] + lane * 8);
  };
  auto stageB = [&](int buf, int half, int k0) {   // one 128-row half, 2 instr/wave
#pragma unroll
    for (int i = 0; i < 2; ++i)
      gload_lds16(W + (size_t)(n0 + half * 128 + w * 16 + i * 8 + l3) * 2048 + k0 + gcol,
                  &sB[buf][(size_t)(half * 128 + w * 16 + i * 8) * 64] + lane * 8);
  };
  auto rdA = [&](const bf16_t* sAx, int mf, int kk) -> short8 {
    return *(const short8*)(sAx + (wm * 64 + mf * 16 + m16) * 64 +
                            ((kk * 4 + quad) ^ swz7) * 8);
  };
  auto rdB = [&](const bf16_t* sBx, int nf, int kk) -> short8 {
    return *(const short8*)(sBx + (wn * 64 + nf * 16 + m16) * 64 +
                            ((kk * 4 + quad) ^ swz7) * 8);
  };

  // prologue: stage tiles 0 and 1; drain tile 0 (leave tile 1's 6 in flight).
  stageA(0, 0);
  stageB(0, 0, 0); stageB(0, 1, 0);
  stageA(1, 64);
  stageB(1, 0, 64); stageB(1, 1, 64);
  asm volatile("s_waitcnt vmcnt(6)" ::: "memory");
  __builtin_amdgcn_s_barrier();

  short8 A0[2], A1[2], B0[4], B1[4];
#pragma unroll
  for (int i = 0; i < 2; ++i) A0[i] = rdA(sA[0], i, 0);
#pragma unroll
  for (int j = 0; j < 4; ++j) B0[j] = rdB(sB[0], j, 0);

  for (int t = 0; t < NT; ++t) {
    const int p = t & 1, q = p ^ 1;
    const bf16_t* sAp = sA[p];
    const bf16_t* sBp = sB[p];
    const bf16_t* sAq = sA[q];
    const bf16_t* sBq = sB[q];
    const bool stg = (t + 1 < NT);
    const bool stg2 = (t + 2 < NT);

    // ---- ph0: read A1(kk0); MFMA A0xB0 (acc rows 0-1)
#pragma unroll
    for (int i = 0; i < 2; ++i) A1[i] = rdA(sAp, 2 + i, 0);
    __builtin_amdgcn_s_setprio(1);
#pragma unroll
    for (int i = 0; i < 2; ++i)
#pragma unroll
      for (int j = 0; j < 4; ++j)
        acc[i][j] = __builtin_amdgcn_mfma_f32_16x16x32_bf16(A0[i], B0[j], acc[i][j], 0, 0, 0);
    __builtin_amdgcn_s_setprio(0);

    // ---- ph1: read A0(kk1), B1(kk1); MFMA A1xB0 (acc rows 2-3)
#pragma unroll
    for (int i = 0; i < 2; ++i) A0[i] = rdA(sAp, i, 1);
#pragma unroll
    for (int j = 0; j < 4; ++j) B1[j] = rdB(sBp, j, 1);
    __builtin_amdgcn_s_setprio(1);
#pragma unroll
    for (int i = 0; i < 2; ++i)
#pragma unroll
      for (int j = 0; j < 4; ++j)
        acc[2 + i][j] = __builtin_amdgcn_mfma_f32_16x16x32_bf16(A1[i], B0[j], acc[2 + i][j], 0, 0, 0);
    __builtin_amdgcn_s_setprio(0);

    // ---- ph2: read A1(kk1); MFMA A0xB1 (acc rows 0-1)
#pragma unroll
    for (int i = 0; i < 2; ++i) A1[i] = rdA(sAp, 2 + i, 1);
    __builtin_amdgcn_s_setprio(1);
#pragma unroll
    for (int i = 0; i < 2; ++i)
#pragma unroll
      for (int j = 0; j < 4; ++j)
        acc[i][j] = __builtin_amdgcn_mfma_f32_16x16x32_bf16(A0[i], B1[j], acc[i][j], 0, 0, 0);
    __builtin_amdgcn_s_setprio(0);

    // ---- tile boundary: exact drain of tile t+1's staging (issued ph3 of t-1)
    asm volatile("s_waitcnt vmcnt(0)" ::: "memory");
    __builtin_amdgcn_s_barrier();

    // ---- ph3: read A0,B0 of t+1 from q; stage ALL of tile t+2 -> p; MFMA A1xB1
    if (stg) {
#pragma unroll
      for (int i = 0; i < 2; ++i) A0[i] = rdA(sAq, i, 0);
#pragma unroll
      for (int j = 0; j < 4; ++j) B0[j] = rdB(sBq, j, 0);
    }
    if (stg2) {
      stageA(p, (t + 2) * 64);
      stageB(p, 0, (t + 2) * 64); stageB(p, 1, (t + 2) * 64);
    }
    __builtin_amdgcn_s_setprio(1);
#pragma unroll
    for (int i = 0; i < 2; ++i)
#pragma unroll
      for (int j = 0; j < 4; ++j)
        acc[2 + i][j] = __builtin_amdgcn_mfma_f32_16x16x32_bf16(A1[i], B1[j], acc[2 + i][j], 0, 0, 0);
    __builtin_amdgcn_s_setprio(0);
  }

  // epilogue: fp32 out + bias
#pragma unroll
  for (int mf = 0; mf < 4; ++mf) {
    const int rowb = m0 + wm * 64 + mf * 16 + quad * 4;
#pragma unroll
    for (int nf = 0; nf < 4; ++nf) {
      const int col = n0 + wn * 64 + nf * 16 + m16;
      float bias; float* op;
      if (col < 1024) { bias = bor[col]; op = out + col; }
      else            { bias = boi[col - 1024]; op = out + 4194304 + (col - 1024); }
#pragma unroll
      for (int r = 0; r < 4; ++r)
        op[(size_t)(rowb + r) * 1024] = acc[mf][nf][r] + bias;
    }
  }
}

// ---------------------------------------------------------------- flash attention
// grid (16, B*H), 512 threads = 8 waves. blockIdx.x remapped so consecutive blocks
// (likely CU-co-resident) pair complementary workloads: bx even -> x=bx/2, bx odd ->
// x=15-bx/2; every (even,odd) pair sums to 49 k-tiles. Pure bijection: output-identical.
// Waves 0-3 own 16 q-rows each of subtile A = x*64..; waves 4-7 own B = (31-x)*64.. .
// Shared staged K/V tile, joint k-loop, BK=64. Fixed-max softmax, ones-row-MFMA row sums.
__global__ __launch_bounds__(512, 4) void attn_k(const bf16_t* __restrict__ qk,
                                                 const bf16_t* __restrict__ vt,
                                                 bf16_t* __restrict__ acat) {
  __shared__ __align__(16) bf16_t sK[64 * 128];       // 16 KB
  __shared__ __align__(16) bf16_t sV[144 * 64];       // 18 KB (rows 128..143: ones/zeros)
  __shared__ __align__(16) bf16_t sP[8][16 * 72];     // 18 KB (one slab per wave)
  const int tid = threadIdx.x, lane = tid & 63, w = tid >> 6;
  const int wq = w & 3, sub = w >> 2;                 // sub 0 = subtile A, 1 = subtile B
  const int quad = lane >> 4, m16 = lane & 15;
  const int bx = blockIdx.x;
  const int x = (bx & 1) ? (15 - (bx >> 1)) : (bx >> 1);   // balanced pairing
  const int bh = blockIdx.y, b = bh >> 4, h = bh & 15;
  const size_t qkrow0 = (size_t)b * 2048;
  const int qA = x * 64, qB = (31 - x) * 64;
  const int nT = 32 - x;
  const int swz7 = m16 & 7;
  const int qbase = (sub ? qB : qA) + wq * 16;

  // preset sV rows 128..143: row 128 = ones, rest zeros (constant rows: swizzle-invariant)
  if (tid < 256) {
    const int rr = tid >> 4, cb = (tid & 15) * 4;
    const bf16_t v = __float2bfloat16(rr == 0 ? 1.f : 0.f);
#pragma unroll
    for (int i = 0; i < 4; ++i) sV[(128 + rr) * 64 + cb + i] = v;
  }

  // Q fragments for this wave's 16 rows (A-operand: m=lane&15, k=quad*8+j), d-chunks of 32
  short8 qf[4];
  {
    const bf16_t* qa = qk + (qkrow0 + qbase + m16) * 4096;
#pragma unroll
    for (int kk = 0; kk < 4; ++kk) {
      const int col = (kk >> 1) * 1024 + h * 64 + (kk & 1) * 32 + quad * 8;
      qf[kk] = *(const short8*)(qa + col);
    }
  }
  f32x4 o[9];
#pragma unroll
  for (int j = 0; j < 9; ++j) o[j] = (f32x4){0.f, 0.f, 0.f, 0.f};

  const int qrow = qbase + quad * 4;

  // staging geometry
  const int kl4 = lane >> 4, kl15 = lane & 15;   // K tile: 4 rows/instr (256 B rows)
  const int vl3 = lane >> 3;                     // V tile: 8 rows/instr (128 B rows)
  const int vg7 = ((lane & 7) ^ vl3) * 8;

  for (int t = 0; t < nT; ++t) {
    const int k0 = t * 64;
    __syncthreads();
    // stage K: 64 rows x 128 elem (Kr|Ki of head h); wave w covers rows w*8+i*4+kl4
#pragma unroll
    for (int i = 0; i < 2; ++i) {
      const int row = w * 8 + i * 4 + kl4;
      const int g = kl15 ^ (row & 7);            // low-3 XOR; bit3 of kl15 preserved
      const int col = 2048 + (g >> 3) * 1024 + h * 64 + (g & 7) * 8;
      gload_lds16(qk + (qkrow0 + k0 + row) * 4096 + col,
                  sK + (size_t)(w * 8 + i * 4) * 128 + lane * 8);
    }
    // stage V^T: 128 d-rows x 64 k; wave w covers rows w*16+i*8+vl3
#pragma unroll
    for (int i = 0; i < 2; ++i) {
      const int row = w * 16 + i * 8 + vl3;
      gload_lds16(vt + ((size_t)bh * 128 + row) * 2048 + k0 + vg7,
                  sV + (size_t)(w * 16 + i * 8) * 64 + lane * 8);
    }
    __syncthreads();

    const bool act = sub ? true : (t <= x);      // B-waves always active
    if (act) {
      const bool dg = sub ? (t == nT - 1) : (t == x);

      // ---- S = Qs·K^T (16 q-rows x 64 k)
      f32x4 sv[4];
#pragma unroll
      for (int jt = 0; jt < 4; ++jt) {
        f32x4 a = (f32x4){0.f, 0.f, 0.f, 0.f};
#pragma unroll
        for (int kk = 0; kk < 4; ++kk) {
          short8 kf = *(const short8*)(sK + (jt * 16 + m16) * 128 +
                                       ((kk * 4 + quad) ^ swz7) * 8);
          a = __builtin_amdgcn_mfma_f32_16x16x32_bf16(qf[kk], kf, a, 0, 0, 0);
        }
        sv[jt] = a;
      }

      // ---- fixed-max softmax: P = exp(S), C-layout -> A-layout via per-wave sP
      bf16_t* pw = sP[w];
#pragma unroll
      for (int jt = 0; jt < 4; ++jt)
#pragma unroll
        for (int r = 0; r < 4; ++r) {
          float s = sv[jt][r];
          if (dg && (k0 + jt * 16 + m16 > qrow + r)) s = -1e30f;
          pw[(quad * 4 + r) * 72 + jt * 16 + m16] = __float2bfloat16(__expf(s));
        }
      asm volatile("s_waitcnt lgkmcnt(0)" ::: "memory");  // own-wave P write->read

      // ---- O += P·V (j=8 = ones-row -> row sums l)
#pragma unroll
      for (int kc = 0; kc < 2; ++kc) {
        short8 p = *(const short8*)(pw + m16 * 72 + kc * 32 + quad * 8);
#pragma unroll
        for (int j = 0; j < 9; ++j) {
          short8 vf = *(const short8*)(sV + (j * 16 + m16) * 64 +
                                       ((kc * 4 + quad) ^ swz7) * 8);
          o[j] = __builtin_amdgcn_mfma_f32_16x16x32_bf16(p, vf, o[j], 0, 0, 0);
        }
      }
    }
  }

  // ---- epilogue: l broadcast from lane (quad*16), normalize, write [B,L,2048]=[out_r|out_i]
  float inv[4];
#pragma unroll
  for (int r = 0; r < 4; ++r)
    inv[r] = 1.f / __shfl(o[8][r], lane & 48);
#pragma unroll
  for (int j = 0; j < 8; ++j) {
    const int d = j * 16 + m16;
    const int col = (d < 64) ? (h * 64 + d) : (1024 + h * 64 + (d - 64));
#pragma unroll
    for (int r = 0; r < 4; ++r)
      acat[((size_t)b * 2048 + qrow + r) * 2048 + col] = __float2bfloat16(o[j][r] * inv[r]);
  }
}

// ---------------------------------------------------------------- launch
extern "C" void kernel_launch(void* const* d_in, const int* in_sizes, int n_in,
                              void* d_out, int out_size, void* d_ws, size_t ws_size,
                              hipStream_t stream) {
  const float* xr  = (const float*)d_in[0];
  const float* xi  = (const float*)d_in[1];
  const float* wqr = (const float*)d_in[2];
  const float* wqi = (const float*)d_in[3];
  const float* wkr = (const float*)d_in[4];
  const float* wki = (const float*)d_in[5];
  const float* wvr = (const float*)d_in[6];
  const float* wvi = (const float*)d_in[7];
  const float* wor = (const float*)d_in[8];
  const float* woi = (const float*)d_in[9];
  const float* bor = (const float*)d_in[10];
  const float* boi = (const float*)d_in[11];
  float* out = (float*)d_out;

  char* ws = (char*)d_ws;
  bf16_t* Xcat = (bf16_t*)(ws);                   // 4096x2048   16 MB
  bf16_t* Wqkv = (bf16_t*)(ws + 16777216ull);     // 6144x2048   24 MB
  bf16_t* QKb  = (bf16_t*)(ws + 41943040ull);     // 4096x4096   32 MB
  bf16_t* Vt   = (bf16_t*)(ws + 75497472ull);     // 4096x2048   16 MB (V transposed)
  bf16_t* Acat = (bf16_t*)(ws + 92274688ull);     // 4096x2048   16 MB
  bf16_t* Wo   = (bf16_t*)(ws + 109051904ull);    // 2048x2048    8 MB

  pack_x_k<<<2048, 256, 0, stream>>>(xr, xi, Xcat);
  pack_wqkv_k<<<2048, 256, 0, stream>>>(wqr, wqi, wkr, wki, wvr, wvi, Wqkv);
  pack_wo_k<<<1024, 256, 0, stream>>>(wor, woi, Wo);
  gemm_qkv_k<<<dim3(16, 32), 512, 0, stream>>>(Xcat, Wqkv, QKb, Vt);
  attn_k<<<dim3(16, 32), 512, 0, stream>>>(QKb, Vt, Acat);
  gemm_out_k<<<dim3(32, 8), 512, 0, stream>>>(Acat, Wo, bor, boi, out);
}